// Round 13
// baseline (272.751 us; speedup 1.0000x reference)
//
#include <hip/hip_runtime.h>

// FDTD rollout — SINGLE fused kernel (cooperative), 256 steps in 16 groups
// of TS=16, neighbor-flag sync between groups (R10, proven). NEW: inside a
// group, steps run in PAIRS. Each wave holds a 12-row register window
// (8 owned rows + 2 halo rows per side) of {cur, pv}. Per pair: step A
// computes window rows 1..10, step B rows 2..9 (+12.5% VALU), then ONE
// LDS exchange (8 writes, lgkm barrier, 8 reads) refills all 4 edge rows
// from neighbor waves -> LDS round-trips and barriers halve vs per-step.
// Exchange skipped on each group's last pair (boundary reload covers it).

#define HH 512
#define WW 512
#define HW (HH * WW)
#define TILE 32
#define TS 16
#define NW 8       // waves per block
#define RPT 8      // owned rows per wave
#define WIN 12     // window rows (idx i <-> region row 8w-2+i)
#define PHC ((float)(2.0 * 3.1415926 * 100.0))

// LDS-only barrier: orders ds ops without draining vmcnt (stores in flight).
#define LDS_BARRIER() asm volatile("s_waitcnt lgkmcnt(0)\n\ts_barrier" ::: "memory")

#if __has_builtin(__builtin_amdgcn_update_dpp)
__device__ __forceinline__ float nbrL(float x) {   // value from lane-1 (left)
    int i = __builtin_bit_cast(int, x);
    i = __builtin_amdgcn_update_dpp(i, i, 0x138, 0xf, 0xf, false); // wave_shr:1
    return __builtin_bit_cast(float, i);
}
__device__ __forceinline__ float nbrR(float x) {   // value from lane+1 (right)
    int i = __builtin_bit_cast(int, x);
    i = __builtin_amdgcn_update_dpp(i, i, 0x130, 0xf, 0xf, false); // wave_shl:1
    return __builtin_bit_cast(float, i);
}
#else
__device__ __forceinline__ float nbrL(float x) { return __shfl_up(x, 1, 64); }
__device__ __forceinline__ float nbrR(float x) { return __shfl_down(x, 1, 64); }
#endif

__global__ void fdtd_zero_flags(int* f) { f[threadIdx.x] = 0; }

template<bool EDGE>
__device__ __forceinline__ float rowv(float c, float u, float d, float pvv,
                                      float rrv, float dcv, bool src, float srcv,
                                      bool b0, bool b511, bool c0, bool c511)
{
    const float l = nbrL(c);
    const float r = nbrR(c);
    float v = 2.f * c - pvv + rrv * (((u + d) + (l + r)) - 4.f * c);
    v = src ? srcv : v;
    if (EDGE) {
        // precedence (last wins): row0 < col0 < col511 < row511
        if (b0)   v = c - dcv * (c - d);
        if (c0)   v = c - dcv * (c - r);
        if (c511) v = c - dcv * (c - l);
        if (b511) v = c - dcv * (c - u);
    }
    return v;
}

typedef float (&SBref)[2][NW][2][2][2][64]; // [buf][wave][side][arr][row][lane]

template<bool EDGE>
__device__ __forceinline__ void run_pairs(
    float (&cur)[WIN], float (&pv)[WIN], const float (&rr)[WIN],
    const float (&dcv)[WIN], const bool (&issrc)[WIN],
    unsigned m0, unsigned m511, bool isC0, bool isC511,
    bool keep, float* opBase, int t0, int pairs, int Bn, int w, int lane,
    SBref sb)
{
    const int wup = (w == 0)      ? 0      : w - 1;
    const int sup = (w == 0)      ? 0      : 1;
    const int wdn = (w == NW - 1) ? NW - 1 : w + 1;
    const int sdn = (w == NW - 1) ? 1      : 0;

    for (int p = 0; p < pairs; ++p) {
        const int buf = p & 1;
        const float srcA =
            1500.0f * __sinf(PHC * (float)(Bn + t0 + 2 * p + 2) * 1.0e-4f);
        const float srcB =
            1500.0f * __sinf(PHC * (float)(Bn + t0 + 2 * p + 3) * 1.0e-4f);
        float A[WIN], B[WIN];
        #pragma unroll
        for (int i = 1; i <= 10; ++i)
            A[i] = rowv<EDGE>(cur[i], cur[i - 1], cur[i + 1], pv[i],
                              rr[i], dcv[i], issrc[i], srcA,
                              (m0 >> i) & 1u, (m511 >> i) & 1u, isC0, isC511);
        #pragma unroll
        for (int i = 2; i <= 9; ++i)
            B[i] = rowv<EDGE>(A[i], A[i - 1], A[i + 1], cur[i],
                              rr[i], dcv[i], issrc[i], srcB,
                              (m0 >> i) & 1u, (m511 >> i) & 1u, isC0, isC511);
        if (keep) {
            float* opA = opBase + (size_t)(t0 + 2 * p) * (size_t)HW;
            float* opB = opA + HW;
            #pragma unroll
            for (int j = 0; j < RPT; ++j)
                __hip_atomic_store(opA + j * WW, A[2 + j], __ATOMIC_RELAXED,
                                   __HIP_MEMORY_SCOPE_AGENT);
            #pragma unroll
            for (int j = 0; j < RPT; ++j)
                __hip_atomic_store(opB + j * WW, B[2 + j], __ATOMIC_RELAXED,
                                   __HIP_MEMORY_SCOPE_AGENT);
        }
        if (p < pairs - 1) {
            // publish owned boundary pairs: top rows (idx 2,3), bottom (8,9)
            sb[buf][w][0][0][0][lane] = B[2];
            sb[buf][w][0][0][1][lane] = B[3];
            sb[buf][w][0][1][0][lane] = A[2];
            sb[buf][w][0][1][1][lane] = A[3];
            sb[buf][w][1][0][0][lane] = B[8];
            sb[buf][w][1][0][1][lane] = B[9];
            sb[buf][w][1][1][0][lane] = A[8];
            sb[buf][w][1][1][1][lane] = A[9];
            LDS_BARRIER();
            cur[0]  = sb[buf][wup][sup][0][0][lane];
            cur[1]  = sb[buf][wup][sup][0][1][lane];
            pv[0]   = sb[buf][wup][sup][1][0][lane];
            pv[1]   = sb[buf][wup][sup][1][1][lane];
            cur[10] = sb[buf][wdn][sdn][0][0][lane];
            cur[11] = sb[buf][wdn][sdn][0][1][lane];
            pv[10]  = sb[buf][wdn][sdn][1][0][lane];
            pv[11]  = sb[buf][wdn][sdn][1][1][lane];
        }
        #pragma unroll
        for (int i = 2; i <= 9; ++i) { pv[i] = A[i]; cur[i] = B[i]; }
    }
}

__global__ __launch_bounds__(512)
void fdtd_pair_k(const float* __restrict__ in_out,
                 const float* __restrict__ cmap,
                 const int* __restrict__ locx,
                 const int* __restrict__ locy,
                 const int* __restrict__ pb,
                 const int* __restrict__ pid2,
                 float* __restrict__ out,
                 int steps, int* __restrict__ flags)
{
    __shared__ float sb[2][NW][2][2][2][64];

    const int tid  = threadIdx.x;
    const int lane = tid & 63;
    const int w    = tid >> 6;
    const int bx   = blockIdx.x & 15;
    const int by   = blockIdx.x >> 4;
    const int gx0  = bx * TILE - TS;
    const int gy0  = by * TILE - TS;
    const int gc   = gx0 + lane;
    const int RB   = w * RPT - 2;        // window idx i -> region row RB+i

    const int lx0 = locx[0], ly0 = locy[0];
    const int lx1 = locx[1], ly1 = locy[1];
    const int lx2 = locx[2], ly2 = locy[2];
    const int Bn  = pb[0] * pid2[0];

    float cur[WIN], pv[WIN], rr[WIN], dcv[WIN];
    bool  issrc[WIN];
    unsigned m0 = 0, m511 = 0;
    const bool colOK = (gc >= 0) & (gc < WW);

    // ---- one-time setup over the 12-row window ----
    #pragma unroll
    for (int i = 0; i < WIN; ++i) {
        const int gr = gy0 + RB + i;
        float c = 0.f, ce = 0.f, pp = 0.f;
        if (colOK && gr >= 0 && gr < HH) {
            const int gi = gr * WW + gc;
            c  = cmap[gi];
            ce = in_out[(size_t)HW + gi];  // frame 1 (cur)
            pp = in_out[gi];               // frame 0 (prev)
        }
        cur[i] = ce; pv[i] = pp;
        rr[i]  = 1.0e-8f * c * c;
        dcv[i] = 1.0e-4f * c;
        issrc[i] = (gr == lx0 && gc == ly0) || (gr == lx1 && gc == ly1) ||
                   (gr == lx2 && gc == ly2);
        if (gr == 0)      m0   |= (1u << i);
        if (gr == HH - 1) m511 |= (1u << i);
    }

    const bool edge    = (bx == 0) | (bx == 15) | (by == 0) | (by == 15);
    const bool isC0    = (gc == 0);
    const bool isC511  = (gc == WW - 1);
    // center 32x32: waves 2..5, lanes 16..47 -> owned rows stay valid all
    // group; they store output and keep idx 2..9 across groups.
    const bool keep    = (w >= 2) & (w <= 5) & (lane >= 16) & (lane < 48);
    float* opBase = out + (size_t)(gy0 + w * RPT) * WW + gc;

    for (int t0 = 0; t0 < steps; t0 += TS) {
        const int nk = (steps - t0 < TS) ? (steps - t0) : TS;

        if (t0 > 0) {
            // ---- group boundary: inter-block neighbor-flag sync ----
            asm volatile("s_waitcnt vmcnt(0)" ::: "memory");
            __syncthreads();
            if (tid == 0)
                __hip_atomic_store(&flags[blockIdx.x], t0,
                                   __ATOMIC_RELAXED, __HIP_MEMORY_SCOPE_AGENT);
            if (tid < 8) {
                const int dy[8] = {-1,-1,-1, 0, 0, 1, 1, 1};
                const int dx[8] = {-1, 0, 1,-1, 1,-1, 0, 1};
                const int nby = by + dy[tid];
                const int nbx = bx + dx[tid];
                if (nby >= 0 && nby < 16 && nbx >= 0 && nbx < 16) {
                    const int nb = (nby << 4) | nbx;
                    while (__hip_atomic_load(&flags[nb], __ATOMIC_RELAXED,
                                             __HIP_MEMORY_SCOPE_AGENT) < t0)
                        __builtin_amdgcn_s_sleep(2);
                }
            }
            __syncthreads();
            // reload window rows from the just-written planes. keep threads
            // need only the 4 window-edge rows; others reload all 12.
            const float* cF = out + (size_t)(t0 - 1) * (size_t)HW;
            const float* pF = cF - HW;
            #pragma unroll
            for (int i = 0; i < WIN; ++i) {
                const bool need = (!keep) | (i < 2) | (i > 9);
                if (need) {
                    const int gr = gy0 + RB + i;
                    float ce = 0.f, pp = 0.f;
                    if (colOK && gr >= 0 && gr < HH) {
                        const int gi = gr * WW + gc;
                        ce = __hip_atomic_load(cF + gi, __ATOMIC_RELAXED,
                                               __HIP_MEMORY_SCOPE_AGENT);
                        pp = __hip_atomic_load(pF + gi, __ATOMIC_RELAXED,
                                               __HIP_MEMORY_SCOPE_AGENT);
                    }
                    cur[i] = ce; pv[i] = pp;
                }
            }
        }

        const int pairs = nk >> 1;    // nk = 16 for this problem
        if (!edge)
            run_pairs<false>(cur, pv, rr, dcv, issrc, m0, m511, isC0, isC511,
                             keep, opBase, t0, pairs, Bn, w, lane, sb);
        else
            run_pairs<true>(cur, pv, rr, dcv, issrc, m0, m511, isC0, isC511,
                            keep, opBase, t0, pairs, Bn, w, lane, sb);
    }
}

extern "C" void kernel_launch(void* const* d_in, const int* in_sizes, int n_in,
                              void* d_out, int out_size, void* d_ws, size_t ws_size,
                              hipStream_t stream) {
    const float* in_out = (const float*)d_in[0];   // [steps+2, 1, 512, 512]
    const float* cmap   = (const float*)d_in[1];   // [1,1,512,512]
    const int*   locx   = (const int*)d_in[2];
    const int*   locy   = (const int*)d_in[3];
    const int*   pb     = (const int*)d_in[4];     // bsize1
    const int*   pid2   = (const int*)d_in[5];     // id2
    float*       outp   = (float*)d_out;
    int*         flags  = (int*)d_ws;              // 256 progress flags

    int steps = out_size / HW;

    hipLaunchKernelGGL(fdtd_zero_flags, dim3(1), dim3(256), 0, stream, flags);

    void* args[] = { (void*)&in_out, (void*)&cmap, (void*)&locx, (void*)&locy,
                     (void*)&pb, (void*)&pid2, (void*)&outp, (void*)&steps,
                     (void*)&flags };
    hipLaunchCooperativeKernel((const void*)fdtd_pair_k,
                               dim3((HH / TILE) * (WW / TILE)),  // 256 blocks
                               dim3(512), args, 0, stream);
}

// Round 14
// 216.793 us; speedup vs baseline: 1.2581x; 1.2581x over previous
//
#include <hip/hip_runtime.h>

// FDTD rollout — SINGLE fused kernel (cooperative, flag-synced groups of
// TS=16; R10 structure) with an INSTRUCTION DIET:
//  - steps unrolled in pairs, new frame written in place over prev (A/B role
//    swap, zero rotation movs)
//  - source sin values precomputed into an LDS table; consumed only by the
//    <=3 waves holding a source (uniform __any branch)
//  - row-0/row-511 boundary overrides reduced to two uniform bools
//    (geometry: only (by==0,w==2,j==0) and (by==15,w==5,j==7) qualify);
//    column overrides only in bx==0/15 blocks (template)
//  - pure interior wave step: 8 rows x (2 DPP + 6 VALU) + 4 LDS + 8 stores.

#define HH 512
#define WW 512
#define HW (HH * WW)
#define TILE 32
#define TS 16
#define NW 8      // waves per block
#define RPT 8     // rows per thread
#define PHC ((float)(2.0 * 3.1415926 * 100.0))

#define LDS_BARRIER() asm volatile("s_waitcnt lgkmcnt(0)\n\ts_barrier" ::: "memory")

#if __has_builtin(__builtin_amdgcn_update_dpp)
__device__ __forceinline__ float nbrL(float x) {   // value from lane-1 (left)
    int i = __builtin_bit_cast(int, x);
    i = __builtin_amdgcn_update_dpp(i, i, 0x138, 0xf, 0xf, false); // wave_shr:1
    return __builtin_bit_cast(float, i);
}
__device__ __forceinline__ float nbrR(float x) {   // value from lane+1 (right)
    int i = __builtin_bit_cast(int, x);
    i = __builtin_amdgcn_update_dpp(i, i, 0x130, 0xf, 0xf, false); // wave_shl:1
    return __builtin_bit_cast(float, i);
}
#else
__device__ __forceinline__ float nbrL(float x) { return __shfl_up(x, 1, 64); }
__device__ __forceinline__ float nbrR(float x) { return __shfl_down(x, 1, 64); }
#endif

__global__ void fdtd_zero_flags(int* f) { f[threadIdx.x] = 0; }

// One step: reads cur=X (+halo via sbR), prev=Y; writes new frame into Y.
template<bool COLEDGE>
__device__ __forceinline__ void fstep(
    float (&X)[RPT], float (&Y)[RPT],
    const float (&rr)[RPT], const float (&dcv)[RPT],
    const float (*sbR)[2][64], float (*sbW)[2][64],
    int lane, int w, int wup, int sup, int wdn, int sdn,
    bool topw, bool botw, bool isC0, bool isC511,
    bool whs, unsigned smask, const float (&srcT)[260], int n,
    bool keep, float* op)
{
    const float upb = sbR[wup][sup][lane];
    const float dnb = sbR[wdn][sdn][lane];
    #pragma unroll
    for (int j = 0; j < RPT; ++j) {
        const float c = X[j];
        const float u = (j == 0)       ? upb : X[j - 1];
        const float d = (j == RPT - 1) ? dnb : X[j + 1];
        const float lft = nbrL(c);
        const float rgt = nbrR(c);
        Y[j] = 2.f * c - Y[j] + rr[j] * (((u + d) + (lft + rgt)) - 4.f * c);
    }
    if (whs) {                       // only waves containing a source
        const float srcv = srcT[n];
        #pragma unroll
        for (int j = 0; j < RPT; ++j)
            if ((smask >> j) & 1u) Y[j] = srcv;
    }
    // precedence (last wins): row0 < col0 < col511 < row511
    if (topw) Y[0] = X[0] - dcv[0] * (X[0] - X[1]);
    if (COLEDGE) {
        #pragma unroll
        for (int j = 0; j < RPT; ++j) {
            const float c   = X[j];
            const float rgt = nbrR(c);
            const float lft = nbrL(c);
            float v = Y[j];
            v = isC0   ? (c - dcv[j] * (c - rgt)) : v;
            v = isC511 ? (c - dcv[j] * (c - lft)) : v;
            Y[j] = v;
        }
    }
    if (botw) Y[RPT - 1] = X[RPT - 1] - dcv[RPT - 1] * (X[RPT - 1] - X[RPT - 2]);
    sbW[w][0][lane] = Y[0];
    sbW[w][1][lane] = Y[RPT - 1];
    if (keep) {
        #pragma unroll
        for (int j = 0; j < RPT; ++j)
            __hip_atomic_store(op + j * WW, Y[j], __ATOMIC_RELAXED,
                               __HIP_MEMORY_SCOPE_AGENT);
    }
    LDS_BARRIER();
}

__global__ __launch_bounds__(512)
void fdtd_diet(const float* __restrict__ in_out,
               const float* __restrict__ cmap,
               const int* __restrict__ locx,
               const int* __restrict__ locy,
               const int* __restrict__ pb,
               const int* __restrict__ pid2,
               float* __restrict__ out,
               int steps, int* __restrict__ flags)
{
    __shared__ float sb[2][NW][2][64];   // [buf][wave][top/bottom row][col]
    __shared__ float srcT[260];          // source value per global step n

    const int tid  = threadIdx.x;
    const int lane = tid & 63;
    const int w    = tid >> 6;
    const int bx   = blockIdx.x & 15;
    const int by   = blockIdx.x >> 4;
    const int gx0  = bx * TILE - TS;
    const int gy0  = by * TILE - TS;
    const int gc   = gx0 + lane;
    const int R    = w * RPT;

    const int lx0 = locx[0], ly0 = locy[0];
    const int lx1 = locx[1], ly1 = locy[1];
    const int lx2 = locx[2], ly2 = locy[2];
    const int Bn  = pb[0] * pid2[0];

    if (tid <= steps && tid < 260)
        srcT[tid] = 1500.0f * __sinf(PHC * (float)(Bn + tid + 1) * 1.0e-4f);

    float A[RPT], B[RPT], rr[RPT], dcv[RPT];
    unsigned smask = 0;
    const bool colOK = (gc >= 0) & (gc < WW);

    #pragma unroll
    for (int j = 0; j < RPT; ++j) {
        const int gr = gy0 + R + j;
        float c = 0.f, ce = 0.f, pp = 0.f;
        if (colOK && gr >= 0 && gr < HH) {
            const int gi = gr * WW + gc;
            c  = cmap[gi];
            ce = in_out[(size_t)HW + gi];  // frame 1 (cur)
            pp = in_out[gi];               // frame 0 (prev)
        }
        A[j] = ce; B[j] = pp;
        rr[j]  = 1.0e-8f * c * c;
        dcv[j] = 1.0e-4f * c;
        if ((gr == lx0 && gc == ly0) || (gr == lx1 && gc == ly1) ||
            (gr == lx2 && gc == ly2)) smask |= (1u << j);
    }
    const bool whs     = __any((int)(smask != 0));
    const bool topw    = (by == 0)  && (w == 2);   // owns global row 0 (j=0)
    const bool botw    = (by == 15) && (w == 5);   // owns global row 511 (j=7)
    const bool coledge = (bx == 0) || (bx == 15);
    const bool isC0    = (gc == 0);
    const bool isC511  = (gc == WW - 1);
    const bool keep    = (w >= 2) & (w <= 5) & (lane >= 16) & (lane < 48);
    const int  rowOff  = (gy0 + R) * WW + gc;

    const int wup = (w == 0)      ? 0      : w - 1;
    const int sup = (w == 0)      ? 0      : 1;
    const int wdn = (w == NW - 1) ? NW - 1 : w + 1;
    const int sdn = (w == NW - 1) ? 1      : 0;

    sb[0][w][0][lane] = A[0];
    sb[0][w][1][lane] = A[RPT - 1];
    __syncthreads();

    for (int t0 = 0; t0 < steps; t0 += TS) {
        const int nk = (steps - t0 < TS) ? (steps - t0) : TS;

        if (t0 > 0) {
            // ---- group boundary: inter-block neighbor-flag sync (R10) ----
            asm volatile("s_waitcnt vmcnt(0)" ::: "memory");
            __syncthreads();
            if (tid == 0)
                __hip_atomic_store(&flags[blockIdx.x], t0,
                                   __ATOMIC_RELAXED, __HIP_MEMORY_SCOPE_AGENT);
            if (tid < 8) {
                const int dy[8] = {-1,-1,-1, 0, 0, 1, 1, 1};
                const int dx[8] = {-1, 0, 1,-1, 1,-1, 0, 1};
                const int nby = by + dy[tid];
                const int nbx = bx + dx[tid];
                if (nby >= 0 && nby < 16 && nbx >= 0 && nbx < 16) {
                    const int nb = (nby << 4) | nbx;
                    while (__hip_atomic_load(&flags[nb], __ATOMIC_RELAXED,
                                             __HIP_MEMORY_SCOPE_AGENT) < t0)
                        __builtin_amdgcn_s_sleep(2);
                }
            }
            __syncthreads();
            if (!keep) {     // reload halo-ring threads' cur/prev
                const float* cF = out + (size_t)(t0 - 1) * (size_t)HW;
                const float* pF = cF - HW;
                #pragma unroll
                for (int j = 0; j < RPT; ++j) {
                    const int gr = gy0 + R + j;
                    float ce = 0.f, pp = 0.f;
                    if (colOK && gr >= 0 && gr < HH) {
                        const int gi = gr * WW + gc;
                        ce = __hip_atomic_load(cF + gi, __ATOMIC_RELAXED,
                                               __HIP_MEMORY_SCOPE_AGENT);
                        pp = __hip_atomic_load(pF + gi, __ATOMIC_RELAXED,
                                               __HIP_MEMORY_SCOPE_AGENT);
                    }
                    A[j] = ce; B[j] = pp;
                }
            }
            sb[0][w][0][lane] = A[0];
            sb[0][w][1][lane] = A[RPT - 1];
            __syncthreads();
        }

        float* op = out + (size_t)t0 * (size_t)HW + rowOff;
        if (!coledge) {
            for (int k = 1; k + 1 <= nk; k += 2) {
                fstep<false>(A, B, rr, dcv, sb[0], sb[1], lane, w, wup, sup,
                             wdn, sdn, topw, botw, isC0, isC511, whs, smask,
                             srcT, t0 + k, keep, op);
                op += HW;
                fstep<false>(B, A, rr, dcv, sb[1], sb[0], lane, w, wup, sup,
                             wdn, sdn, topw, botw, isC0, isC511, whs, smask,
                             srcT, t0 + k + 1, keep, op);
                op += HW;
            }
            if (nk & 1) {
                fstep<false>(A, B, rr, dcv, sb[0], sb[1], lane, w, wup, sup,
                             wdn, sdn, topw, botw, isC0, isC511, whs, smask,
                             srcT, t0 + nk, keep, op);
                #pragma unroll
                for (int j = 0; j < RPT; ++j) {
                    const float t = A[j]; A[j] = B[j]; B[j] = t;
                }
            }
        } else {
            for (int k = 1; k + 1 <= nk; k += 2) {
                fstep<true>(A, B, rr, dcv, sb[0], sb[1], lane, w, wup, sup,
                            wdn, sdn, topw, botw, isC0, isC511, whs, smask,
                            srcT, t0 + k, keep, op);
                op += HW;
                fstep<true>(B, A, rr, dcv, sb[1], sb[0], lane, w, wup, sup,
                            wdn, sdn, topw, botw, isC0, isC511, whs, smask,
                            srcT, t0 + k + 1, keep, op);
                op += HW;
            }
            if (nk & 1) {
                fstep<true>(A, B, rr, dcv, sb[0], sb[1], lane, w, wup, sup,
                            wdn, sdn, topw, botw, isC0, isC511, whs, smask,
                            srcT, t0 + nk, keep, op);
                #pragma unroll
                for (int j = 0; j < RPT; ++j) {
                    const float t = A[j]; A[j] = B[j]; B[j] = t;
                }
            }
        }
    }
}

extern "C" void kernel_launch(void* const* d_in, const int* in_sizes, int n_in,
                              void* d_out, int out_size, void* d_ws, size_t ws_size,
                              hipStream_t stream) {
    const float* in_out = (const float*)d_in[0];   // [steps+2, 1, 512, 512]
    const float* cmap   = (const float*)d_in[1];   // [1,1,512,512]
    const int*   locx   = (const int*)d_in[2];
    const int*   locy   = (const int*)d_in[3];
    const int*   pb     = (const int*)d_in[4];     // bsize1
    const int*   pid2   = (const int*)d_in[5];     // id2
    float*       outp   = (float*)d_out;
    int*         flags  = (int*)d_ws;              // 256 progress flags

    int steps = out_size / HW;

    hipLaunchKernelGGL(fdtd_zero_flags, dim3(1), dim3(256), 0, stream, flags);

    void* args[] = { (void*)&in_out, (void*)&cmap, (void*)&locx, (void*)&locy,
                     (void*)&pb, (void*)&pid2, (void*)&outp, (void*)&steps,
                     (void*)&flags };
    hipLaunchCooperativeKernel((const void*)fdtd_diet,
                               dim3((HH / TILE) * (WW / TILE)),  // 256 blocks
                               dim3(512), args, 0, stream);
}